// Round 9
// baseline (59.238 us; speedup 1.0000x reference)
//
#include <hip/hip_runtime.h>
#include <hip/hip_bf16.h>

// y = relu(x @ W + b); x [65536,1024] f32, W [1024,84] f32, b [84] f32.
// R9 = R8 + TRIPLE-buffered W staging (stage(c+2) issued at top of chunk c,
// 2 compute phases of cover) so the end-of-chunk barrier never waits on a
// just-issued stage. LDS 3x24KB=72KB -> still 2 blocks/CU (144KB<160).
// vmcnt per barrier re-derived: steady c=0..5 -> vmcnt(19); c=6 -> vmcnt(8).
// Structure otherwise: prep kernel -> Wt bf16 [96][1024]; global_load_lds
// w=16 XOR-swizzled staging; x reg pipeline half-chunk depth-4; LDS-staged
// coalesced epilogue.

typedef __attribute__((ext_vector_type(4))) float f32x4;
typedef __attribute__((ext_vector_type(8))) short bf16x8;

#define FEAT 1024
#define NOUT 84
#define NPAD 96
#define BATCH 65536
#define CHUNK 128
#define NCHUNK 8                     // 8 chunks, 16 halves
#define ROWB 256                     // bytes per LDS row
#define CHUNK_BYTES (NPAD * ROWB)    // 24576

typedef __attribute__((address_space(3))) unsigned int lds_uint;
typedef __attribute__((address_space(1))) const unsigned int glb_uint;

__device__ __forceinline__ unsigned short f2bf(float f) {
  union { __hip_bfloat16 h; unsigned short u; } c;
  c.h = __float2bfloat16(f);
  return c.u;
}

__global__ __launch_bounds__(256) void prep_kernel(
    const float* __restrict__ W, const float* __restrict__ b,
    unsigned short* __restrict__ Wt, float* __restrict__ bpad) {
  int idx = blockIdx.x * 256 + threadIdx.x;  // 0 .. 98303
  int n = idx >> 10;
  int k = idx & 1023;
  unsigned short v = 0;
  if (n < NOUT) v = f2bf(W[(size_t)k * NOUT + n]);
  Wt[idx] = v;
  if (idx < NPAD) bpad[idx] = (idx < NOUT) ? b[idx] : 0.0f;
}

__global__ __launch_bounds__(512, 4) void gemm_kernel(
    const float* __restrict__ x, const unsigned short* __restrict__ Wt,
    const float* __restrict__ bpad, float* __restrict__ out) {
  __shared__ __align__(16) unsigned char smem[3 * CHUNK_BYTES];  // 72 KB

  const int tid = threadIdx.x;
  const int wave = tid >> 6;
  const int lane = tid & 63;
  const int r = lane & 15;   // A row-in-tile / B col-in-tile / D col
  const int g = lane >> 4;   // k-group / D row-group
  const int row0 = (blockIdx.x * 8 + wave) * 16;
  const int rsw = (r & 7) << 4;

  const float* xp = x + (size_t)(row0 + r) * FEAT + g * 8;

  f32x4 acc[6];
#pragma unroll
  for (int t = 0; t < 6; ++t) acc[t] = (f32x4){0.f, 0.f, 0.f, 0.f};

  // x pipeline: 4 slots x 4 f32x4 (half-chunk K=64 each), all indices static.
  f32x4 xb[16];

  // Stage chunk c of Wt into LDS buffer. Linear LDS dest; source address
  // carries the inverse XOR swizzle (rule #21: both-sides-or-neither).
  auto stage = [&](int c, int buf) {
#pragma unroll
    for (int s = 0; s < 3; ++s) {
      int d = s * 8192 + wave * 1024 + lane * 16;
      int n = d >> 8;
      int cb = d & 255;
      const unsigned char* src = (const unsigned char*)Wt +
          (size_t)n * (FEAT * 2) + c * ROWB + (cb ^ ((n & 7) << 4));
      unsigned char* dst = &smem[buf * CHUNK_BYTES + s * 8192 + wave * 1024];
      __builtin_amdgcn_global_load_lds((glb_uint*)src, (lds_uint*)dst, 16, 0, 0);
    }
  };

  auto loadXhalf = [&](int h) {  // h = 0..15, fills slot h&3
    const float* base = xp + h * 64;
    xb[(h & 3) * 4 + 0] = *(const f32x4*)(base);
    xb[(h & 3) * 4 + 1] = *(const f32x4*)(base + 4);
    xb[(h & 3) * 4 + 2] = *(const f32x4*)(base + 32);
    xb[(h & 3) * 4 + 3] = *(const f32x4*)(base + 36);
  };

  // Prologue: stage(0), stage(1) first, then 4 x half-groups.
  stage(0, 0);
  stage(1, 1);
  __builtin_amdgcn_sched_barrier(0);
  loadXhalf(0);
  loadXhalf(1);
  loadXhalf(2);
  loadXhalf(3);
  __builtin_amdgcn_sched_barrier(0);
  // Retire stage(0) only: younger = stage(1)[3] + x(0..3)[16] = 19.
  asm volatile("s_waitcnt vmcnt(19)" ::: "memory");
  __builtin_amdgcn_s_barrier();
  __builtin_amdgcn_sched_barrier(0);

#pragma unroll
  for (int c = 0; c < NCHUNK; ++c) {
    if (c + 2 < NCHUNK) {
      stage(c + 2, (c + 2) % 3);   // two chunks ahead (triple buffer)
      __builtin_amdgcn_sched_barrier(0);
    }
    const unsigned char* bb = &smem[(c % 3) * CHUNK_BYTES];

#pragma unroll
    for (int hh = 0; hh < 2; ++hh) {
      const int h = 2 * c + hh;
      // Pack A fragments for half h (compiler-counted vmcnt wait on x(h)).
      bf16x8 af[2];
#pragma unroll
      for (int kk = 0; kk < 2; ++kk) {
        f32x4 a0 = xb[(h & 3) * 4 + kk * 2];
        f32x4 a1 = xb[(h & 3) * 4 + kk * 2 + 1];
        bf16x8 v;
        v[0] = (short)f2bf(a0[0]); v[1] = (short)f2bf(a0[1]);
        v[2] = (short)f2bf(a0[2]); v[3] = (short)f2bf(a0[3]);
        v[4] = (short)f2bf(a1[0]); v[5] = (short)f2bf(a1[1]);
        v[6] = (short)f2bf(a1[2]); v[7] = (short)f2bf(a1[3]);
        af[kk] = v;
      }
      // Refill the freed slot 4 halves ahead.
      if (h + 4 < 2 * NCHUNK) {
        loadXhalf(h + 4);
        __builtin_amdgcn_sched_barrier(0);
      }
      // 12 MFMA for this half (ksteps kp = hh*2 + kk).
#pragma unroll
      for (int kk = 0; kk < 2; ++kk) {
        const int kp = hh * 2 + kk;
#pragma unroll
        for (int t = 0; t < 6; ++t) {
          int addr = (t * 16 + r) * ROWB + ((kp * 64 + g * 16) ^ rsw);
          bf16x8 bf = *(const bf16x8*)(bb + addr);
          acc[t] = __builtin_amdgcn_mfma_f32_16x16x32_bf16(af[kk], bf, acc[t], 0, 0, 0);
        }
      }
    }

    if (c + 1 < NCHUNK) {
      if (c <= NCHUNK - 3) {
        // Retire stage(c+1) (issued top of chunk c-1 / prologue). Younger:
        // x(2c+2)[4] + x(2c+3)[4] + stage(c+2)[3] + x(2c+4)[4] + x(2c+5)[4]
        // = 19 (all exist for c<=5).
        asm volatile("s_waitcnt vmcnt(19)" ::: "memory");
      } else {
        // c == 6: stages/refills have stopped. Younger than stage(7):
        // x(14)[4] + x(15)[4] = 8.
        asm volatile("s_waitcnt vmcnt(8)" ::: "memory");
      }
      __builtin_amdgcn_s_barrier();
      __builtin_amdgcn_sched_barrier(0);
    }
  }

  // Epilogue: stage bias+ReLU output in LDS ([128][84] f32 = 43008 B),
  // stream out the block's contiguous span as coalesced dwordx4.
  __syncthreads();
  float* osm = (float*)smem;
#pragma unroll
  for (int t = 0; t < 6; ++t) {
    int col = t * 16 + r;
    if (col < NOUT) {
      float bias = bpad[col];
#pragma unroll
      for (int j = 0; j < 4; ++j) {
        float v = acc[t][j] + bias;
        v = v > 0.f ? v : 0.f;
        osm[(wave * 16 + g * 4 + j) * NOUT + col] = v;
      }
    }
  }
  __syncthreads();

  f32x4* op = (f32x4*)(out + (size_t)blockIdx.x * 128 * NOUT);
  const f32x4* sp = (const f32x4*)osm;
#pragma unroll
  for (int i = 0; i < 6; ++i) {
    int idx = i * 512 + tid;
    if (idx < (128 * NOUT) / 4) op[idx] = sp[idx];
  }
}

extern "C" void kernel_launch(void* const* d_in, const int* in_sizes, int n_in,
                              void* d_out, int out_size, void* d_ws, size_t ws_size,
                              hipStream_t stream) {
  const float* x = (const float*)d_in[0];
  const float* W = (const float*)d_in[1];
  const float* b = (const float*)d_in[2];
  float* out = (float*)d_out;

  unsigned short* Wt = (unsigned short*)d_ws;                    // 96*1024 bf16
  float* bpad = (float*)((char*)d_ws + (size_t)NPAD * FEAT * 2); // 96 f32

  prep_kernel<<<(NPAD * FEAT) / 256, 256, 0, stream>>>(W, b, Wt, bpad);
  gemm_kernel<<<BATCH / 128, 512, 0, stream>>>(x, Wt, bpad, out);
}

// Round 10
// 54.303 us; speedup vs baseline: 1.0909x; 1.0909x over previous
//
#include <hip/hip_runtime.h>
#include <hip/hip_bf16.h>

// y = relu(x @ W + b); x [65536,1024] f32, W [1024,84] f32, b [84] f32.
// R10 = R8 (best: 57.3us) + nontemporal epilogue stores: output is written
// once and never re-read; nt keeps it from evicting x (exactly L3-sized,
// ~50% L3-resident across replays per R1 FETCH_SIZE=135MB evidence).
// Structure: prep kernel -> Wt bf16 [96][1024]; gemm stages Wt to LDS per
// 128-k chunk (global_load_lds w=16, XOR-swizzled source, double-buffered,
// counted vmcnt barriers: 8 steady / 0 at drain); x reg pipeline half-chunk
// depth-4; LDS-staged coalesced epilogue.

typedef __attribute__((ext_vector_type(4))) float f32x4;
typedef __attribute__((ext_vector_type(8))) short bf16x8;

#define FEAT 1024
#define NOUT 84
#define NPAD 96
#define BATCH 65536
#define CHUNK 128
#define NCHUNK 8                     // 8 chunks, 16 halves
#define ROWB 256                     // bytes per LDS row
#define CHUNK_BYTES (NPAD * ROWB)    // 24576

typedef __attribute__((address_space(3))) unsigned int lds_uint;
typedef __attribute__((address_space(1))) const unsigned int glb_uint;

__device__ __forceinline__ unsigned short f2bf(float f) {
  union { __hip_bfloat16 h; unsigned short u; } c;
  c.h = __float2bfloat16(f);
  return c.u;
}

__global__ __launch_bounds__(256) void prep_kernel(
    const float* __restrict__ W, const float* __restrict__ b,
    unsigned short* __restrict__ Wt, float* __restrict__ bpad) {
  int idx = blockIdx.x * 256 + threadIdx.x;  // 0 .. 98303
  int n = idx >> 10;
  int k = idx & 1023;
  unsigned short v = 0;
  if (n < NOUT) v = f2bf(W[(size_t)k * NOUT + n]);
  Wt[idx] = v;
  if (idx < NPAD) bpad[idx] = (idx < NOUT) ? b[idx] : 0.0f;
}

__global__ __launch_bounds__(512, 4) void gemm_kernel(
    const float* __restrict__ x, const unsigned short* __restrict__ Wt,
    const float* __restrict__ bpad, float* __restrict__ out) {
  __shared__ __align__(16) unsigned char smem[2 * CHUNK_BYTES];  // 48 KB

  const int tid = threadIdx.x;
  const int wave = tid >> 6;
  const int lane = tid & 63;
  const int r = lane & 15;   // A row-in-tile / B col-in-tile / D col
  const int g = lane >> 4;   // k-group / D row-group
  const int row0 = (blockIdx.x * 8 + wave) * 16;
  const int rsw = (r & 7) << 4;

  const float* xp = x + (size_t)(row0 + r) * FEAT + g * 8;

  f32x4 acc[6];
#pragma unroll
  for (int t = 0; t < 6; ++t) acc[t] = (f32x4){0.f, 0.f, 0.f, 0.f};

  // x pipeline: 4 slots x 4 f32x4 (half-chunk K=64 each), all indices static.
  f32x4 xb[16];

  // Stage chunk c of Wt into LDS buffer. Linear LDS dest; source address
  // carries the inverse XOR swizzle (rule #21: both-sides-or-neither).
  auto stage = [&](int c, int buf) {
#pragma unroll
    for (int s = 0; s < 3; ++s) {
      int d = s * 8192 + wave * 1024 + lane * 16;
      int n = d >> 8;
      int cb = d & 255;
      const unsigned char* src = (const unsigned char*)Wt +
          (size_t)n * (FEAT * 2) + c * ROWB + (cb ^ ((n & 7) << 4));
      unsigned char* dst = &smem[buf * CHUNK_BYTES + s * 8192 + wave * 1024];
      __builtin_amdgcn_global_load_lds((glb_uint*)src, (lds_uint*)dst, 16, 0, 0);
    }
  };

  auto loadXhalf = [&](int h) {  // h = 0..15, fills slot h&3
    const float* base = xp + h * 64;
    xb[(h & 3) * 4 + 0] = *(const f32x4*)(base);
    xb[(h & 3) * 4 + 1] = *(const f32x4*)(base + 4);
    xb[(h & 3) * 4 + 2] = *(const f32x4*)(base + 32);
    xb[(h & 3) * 4 + 3] = *(const f32x4*)(base + 36);
  };

  // Prologue: stage(0) first (oldest in FIFO), then 4 x half-groups.
  stage(0, 0);
  __builtin_amdgcn_sched_barrier(0);
  loadXhalf(0);
  loadXhalf(1);
  loadXhalf(2);
  loadXhalf(3);
  __builtin_amdgcn_sched_barrier(0);
  // Retire only stage(0) (oldest 3 of 19); x loads stay in flight.
  asm volatile("s_waitcnt vmcnt(16)" ::: "memory");
  __builtin_amdgcn_s_barrier();
  __builtin_amdgcn_sched_barrier(0);

#pragma unroll
  for (int c = 0; c < NCHUNK; ++c) {
    if (c + 1 < NCHUNK) {
      stage(c + 1, (c + 1) & 1);
      __builtin_amdgcn_sched_barrier(0);
    }
    const unsigned char* bb = &smem[(c & 1) * CHUNK_BYTES];

#pragma unroll
    for (int hh = 0; hh < 2; ++hh) {
      const int h = 2 * c + hh;
      // Pack A fragments for half h (compiler-counted vmcnt wait on x(h)).
      bf16x8 af[2];
#pragma unroll
      for (int kk = 0; kk < 2; ++kk) {
        f32x4 a0 = xb[(h & 3) * 4 + kk * 2];
        f32x4 a1 = xb[(h & 3) * 4 + kk * 2 + 1];
        bf16x8 v;
        v[0] = (short)f2bf(a0[0]); v[1] = (short)f2bf(a0[1]);
        v[2] = (short)f2bf(a0[2]); v[3] = (short)f2bf(a0[3]);
        v[4] = (short)f2bf(a1[0]); v[5] = (short)f2bf(a1[1]);
        v[6] = (short)f2bf(a1[2]); v[7] = (short)f2bf(a1[3]);
        af[kk] = v;
      }
      // Refill the freed slot 4 halves ahead.
      if (h + 4 < 2 * NCHUNK) {
        loadXhalf(h + 4);
        __builtin_amdgcn_sched_barrier(0);
      }
      // 12 MFMA for this half (ksteps kp = hh*2 + kk).
#pragma unroll
      for (int kk = 0; kk < 2; ++kk) {
        const int kp = hh * 2 + kk;
#pragma unroll
        for (int t = 0; t < 6; ++t) {
          int addr = (t * 16 + r) * ROWB + ((kp * 64 + g * 16) ^ rsw);
          bf16x8 bf = *(const bf16x8*)(bb + addr);
          acc[t] = __builtin_amdgcn_mfma_f32_16x16x32_bf16(af[kk], bf, acc[t], 0, 0, 0);
        }
      }
    }

    if (c + 1 < NCHUNK) {
      if (c < NCHUNK - 2) {
        // Outstanding (oldest->youngest): x(2c+2)[4], x(2c+3)[4],
        // stage(c+1)[3], x(2c+4)[4], x(2c+5)[4]. vmcnt(8) retires through
        // the stage; the 8 refills stay in flight.
        asm volatile("s_waitcnt vmcnt(8)" ::: "memory");
      } else {
        // c == 6: refills stopped, stage(7) is the YOUNGEST of 11
        // outstanding -> must drain fully to guarantee it landed.
        asm volatile("s_waitcnt vmcnt(0)" ::: "memory");
      }
      __builtin_amdgcn_s_barrier();
      __builtin_amdgcn_sched_barrier(0);
    }
  }

  // Epilogue: stage bias+ReLU output in LDS ([128][84] f32 = 43008 B),
  // stream out the block's contiguous span as coalesced NONTEMPORAL dwordx4
  // (output is never re-read; keep it out of L2/L3 so x stays resident).
  __syncthreads();
  float* osm = (float*)smem;
#pragma unroll
  for (int t = 0; t < 6; ++t) {
    int col = t * 16 + r;
    if (col < NOUT) {
      float bias = bpad[col];
#pragma unroll
      for (int j = 0; j < 4; ++j) {
        float v = acc[t][j] + bias;
        v = v > 0.f ? v : 0.f;
        osm[(wave * 16 + g * 4 + j) * NOUT + col] = v;
      }
    }
  }
  __syncthreads();

  f32x4* op = (f32x4*)(out + (size_t)blockIdx.x * 128 * NOUT);
  const f32x4* sp = (const f32x4*)osm;
#pragma unroll
  for (int i = 0; i < 6; ++i) {
    int idx = i * 512 + tid;
    if (idx < (128 * NOUT) / 4) __builtin_nontemporal_store(sp[idx], &op[idx]);
  }
}

extern "C" void kernel_launch(void* const* d_in, const int* in_sizes, int n_in,
                              void* d_out, int out_size, void* d_ws, size_t ws_size,
                              hipStream_t stream) {
  const float* x = (const float*)d_in[0];
  const float* W = (const float*)d_in[1];
  const float* b = (const float*)d_in[2];
  float* out = (float*)d_out;

  unsigned short* Wt = (unsigned short*)d_ws;                    // 96*1024 bf16
  float* bpad = (float*)((char*)d_ws + (size_t)NPAD * FEAT * 2); // 96 f32

  prep_kernel<<<(NPAD * FEAT) / 256, 256, 0, stream>>>(W, b, Wt, bpad);
  gemm_kernel<<<BATCH / 128, 512, 0, stream>>>(x, Wt, bpad, out);
}